// Round 1
// baseline (2068.330 us; speedup 1.0000x reference)
//
#include <hip/hip_runtime.h>
#include <hip/hip_bf16.h>

#define E_TOTAL 500000

typedef __attribute__((ext_vector_type(8))) short bf16x8;
typedef __attribute__((ext_vector_type(4))) float f32x4;

#define MFMA(a, b, c) __builtin_amdgcn_mfma_f32_16x16x32_bf16((a), (b), (c), 0, 0, 0)

__device__ __forceinline__ unsigned short f2b(float f) {
    return __builtin_bit_cast(unsigned short, __float2bfloat16(f));
}
__device__ __forceinline__ float b2f(unsigned short s) {
    return __bfloat162float(__builtin_bit_cast(__hip_bfloat16, s));
}

// Phase-aliased LDS. P1: concat input x1 [64 rows][384+8 pad] bf16.
// P2: y (post-mlp1), h (bf16 copy), h_new — all [64][128+8 pad] bf16.
// y/hbf writes happen only after a barrier that ends all x1 reads.
struct P1 { unsigned short x1[64][392]; };                       // 50176 B
struct P2 { unsigned short y[64][136];                           // 17408 B
            unsigned short hbf[64][136];                         // 17408 B
            unsigned short hnew[64][136]; };                     // 17408 B
union SmemU { P1 p1; P2 p2; };                                   // 52224 B

// f32 -> bf16 weight pre-conversion into workspace (runs every call; cheap).
__global__ void wconv_kernel(const float* __restrict__ W1, const float* __restrict__ Wih,
                             const float* __restrict__ Whh, const float* __restrict__ Wx,
                             unsigned short* __restrict__ out) {
    int i = blockIdx.x * 256 + threadIdx.x;
    if (i >= 155648) return;
    float v;
    if      (i < 49152)  v = W1[i];
    else if (i < 98304)  v = Wih[i - 49152];
    else if (i < 147456) v = Whh[i - 98304];
    else                 v = Wx[i - 147456];
    out[i] = f2b(v);
}

__global__ __launch_bounds__(256) void edge_model_kernel(
    const float* __restrict__ src, const float* __restrict__ dst,
    const float* __restrict__ eat, const float* __restrict__ hin,
    const float* __restrict__ u, const int* __restrict__ batch,
    const float* __restrict__ winding,
    const float* __restrict__ Ww, const float* __restrict__ bw,
    const float* __restrict__ gw, const float* __restrict__ betaw,
    const float* __restrict__ b1, const float* __restrict__ g1,
    const float* __restrict__ beta1,
    const float* __restrict__ bih, const float* __restrict__ bhh,
    const float* __restrict__ bx,
    const unsigned short* __restrict__ W1bf, const unsigned short* __restrict__ Wihbf,
    const unsigned short* __restrict__ Whhbf, const unsigned short* __restrict__ Wxbf,
    float* __restrict__ xout, float* __restrict__ hout)
{
    __shared__ SmemU sm;
    const int tid  = threadIdx.x;
    const int e0   = blockIdx.x * 64;
    const int lane = tid & 63;
    const int lhi  = lane >> 4;       // 0..3
    const int llo  = lane & 15;       // 0..15
    const int m0   = (tid >> 6) * 16; // wave's 16-row base

    // ---------------- Phase 1: build x1 = [src|dst|eat|u[batch]|w] ----------------
    #pragma unroll
    for (int it = 0; it < 4; ++it) {
        int q   = it * 256 + tid;            // 1024 float4-quads per source
        int row = q >> 4;
        int c4  = (q & 15) << 2;
        long e  = min(e0 + row, E_TOTAL - 1);
        float4 a = *(const float4*)(src + e * 64 + c4);
        float4 b = *(const float4*)(dst + e * 64 + c4);
        float4 c = *(const float4*)(eat + e * 64 + c4);
        int bi   = batch[e];
        float4 d = *(const float4*)(u + (long)bi * 64 + c4);
        unsigned short* xr = sm.p1.x1[row];
        ushort4 pa; pa.x=f2b(a.x); pa.y=f2b(a.y); pa.z=f2b(a.z); pa.w=f2b(a.w);
        ushort4 pb; pb.x=f2b(b.x); pb.y=f2b(b.y); pb.z=f2b(b.z); pb.w=f2b(b.w);
        ushort4 pc; pc.x=f2b(c.x); pc.y=f2b(c.y); pc.z=f2b(c.z); pc.w=f2b(c.w);
        ushort4 pd; pd.x=f2b(d.x); pd.y=f2b(d.y); pd.z=f2b(d.z); pd.w=f2b(d.w);
        *(ushort4*)(xr + c4)       = pa;
        *(ushort4*)(xr + 64 + c4)  = pb;
        *(ushort4*)(xr + 128 + c4) = pc;
        *(ushort4*)(xr + 192 + c4) = pd;
    }
    {   // winding MLP: Linear(2->128) + LN + ReLU. 4 threads per row, shuffle-reduce.
        int row = tid >> 2;
        int seg = tid & 3;
        long e  = min(e0 + row, E_TOTAL - 1);
        float wi0 = winding[e * 2], wi1 = winding[e * 2 + 1];
        float vals[32]; float s = 0.f, s2 = 0.f;
        #pragma unroll
        for (int j = 0; j < 32; ++j) {
            int jj = seg * 32 + j;
            float v = fmaf(wi0, Ww[2 * jj], fmaf(wi1, Ww[2 * jj + 1], bw[jj]));
            vals[j] = v; s += v; s2 += v * v;
        }
        s  += __shfl_xor(s, 1);  s  += __shfl_xor(s, 2);
        s2 += __shfl_xor(s2, 1); s2 += __shfl_xor(s2, 2);
        float mean = s * (1.f / 128.f);
        float var  = fmaxf(s2 * (1.f / 128.f) - mean * mean, 0.f);
        float inv  = rsqrtf(var + 1e-5f);
        #pragma unroll
        for (int j = 0; j < 32; ++j) {
            int jj = seg * 32 + j;
            float v = (vals[j] - mean) * inv * gw[jj] + betaw[jj];
            sm.p1.x1[row][256 + jj] = f2b(fmaxf(v, 0.f));
        }
    }
    __syncthreads();

    // ---------------- Phase 2: y = relu(LN(x1 @ W1^T + b1)) ----------------
    f32x4 acc[8];
    #pragma unroll
    for (int nt = 0; nt < 8; ++nt) acc[nt] = (f32x4){0.f, 0.f, 0.f, 0.f};
    {
        const unsigned short* wp = W1bf + (size_t)llo * 384 + lhi * 8;
        for (int k0 = 0; k0 < 384; k0 += 32) {
            bf16x8 a = *(const bf16x8*)&sm.p1.x1[m0 + llo][k0 + lhi * 8];
            #pragma unroll
            for (int nt = 0; nt < 8; ++nt) {
                bf16x8 b = *(const bf16x8*)(wp + nt * 16 * 384 + k0);
                acc[nt] = MFMA(a, b, acc[nt]);
            }
        }
    }
    {
        #pragma unroll
        for (int nt = 0; nt < 8; ++nt) {
            float bias = b1[nt * 16 + llo];
            #pragma unroll
            for (int r = 0; r < 4; ++r) acc[nt][r] += bias;
        }
        float mean[4], inv[4];
        #pragma unroll
        for (int r = 0; r < 4; ++r) {   // in-register LN: reduce over 8 regs x 16 lanes
            float s = 0.f, s2 = 0.f;
            #pragma unroll
            for (int nt = 0; nt < 8; ++nt) { float v = acc[nt][r]; s += v; s2 += v * v; }
            #pragma unroll
            for (int m = 1; m < 16; m <<= 1) { s += __shfl_xor(s, m); s2 += __shfl_xor(s2, m); }
            mean[r] = s * (1.f / 128.f);
            float var = fmaxf(s2 * (1.f / 128.f) - mean[r] * mean[r], 0.f);
            inv[r] = rsqrtf(var + 1e-5f);
        }
        __syncthreads();   // all x1 reads done everywhere; safe to switch LDS to P2 layout
        #pragma unroll
        for (int nt = 0; nt < 8; ++nt) {
            int n = nt * 16 + llo;
            float g = g1[n], be = beta1[n];
            #pragma unroll
            for (int r = 0; r < 4; ++r) {
                float v = (acc[nt][r] - mean[r]) * inv[r] * g + be;
                sm.p2.y[m0 + lhi * 4 + r][n] = f2b(fmaxf(v, 0.f));
            }
        }
    }

    // ---------------- Phase 3: stage h tile as bf16 ----------------
    #pragma unroll
    for (int it = 0; it < 8; ++it) {
        int q   = it * 256 + tid;            // 2048 float4-quads
        int row = q >> 5;
        int c4  = (q & 31) << 2;
        long e  = min(e0 + row, E_TOTAL - 1);
        float4 v = *(const float4*)(hin + e * 128 + c4);
        ushort4 p; p.x=f2b(v.x); p.y=f2b(v.y); p.z=f2b(v.z); p.w=f2b(v.w);
        *(ushort4*)(sm.p2.hbf[row] + c4) = p;
    }
    __syncthreads();

    // ---------------- Phase 4: GRU gates ----------------
    f32x4 gr[8], gz[8], gin[8], ghn[8];
    #pragma unroll
    for (int nt = 0; nt < 8; ++nt) {
        gr[nt] = (f32x4){0.f,0.f,0.f,0.f}; gz[nt] = (f32x4){0.f,0.f,0.f,0.f};
        gin[nt] = (f32x4){0.f,0.f,0.f,0.f}; ghn[nt] = (f32x4){0.f,0.f,0.f,0.f};
    }
    {
        const unsigned short* wip = Wihbf + (size_t)llo * 128 + lhi * 8;
        const unsigned short* whp = Whhbf + (size_t)llo * 128 + lhi * 8;
        for (int k0 = 0; k0 < 128; k0 += 32) {
            bf16x8 ay = *(const bf16x8*)&sm.p2.y[m0 + llo][k0 + lhi * 8];
            bf16x8 ah = *(const bf16x8*)&sm.p2.hbf[m0 + llo][k0 + lhi * 8];
            #pragma unroll
            for (int nt = 0; nt < 8; ++nt) {
                bf16x8 br = *(const bf16x8*)(wip + (nt * 16) * 128 + k0);
                bf16x8 bz = *(const bf16x8*)(wip + (128 + nt * 16) * 128 + k0);
                bf16x8 bn = *(const bf16x8*)(wip + (256 + nt * 16) * 128 + k0);
                gr[nt]  = MFMA(ay, br, gr[nt]);
                gz[nt]  = MFMA(ay, bz, gz[nt]);
                gin[nt] = MFMA(ay, bn, gin[nt]);
                bf16x8 hr = *(const bf16x8*)(whp + (nt * 16) * 128 + k0);
                bf16x8 hz = *(const bf16x8*)(whp + (128 + nt * 16) * 128 + k0);
                bf16x8 hn = *(const bf16x8*)(whp + (256 + nt * 16) * 128 + k0);
                gr[nt]  = MFMA(ah, hr, gr[nt]);
                gz[nt]  = MFMA(ah, hz, gz[nt]);
                ghn[nt] = MFMA(ah, hn, ghn[nt]);
            }
        }
    }
    #pragma unroll
    for (int nt = 0; nt < 8; ++nt) {
        int n = nt * 16 + llo;
        float br_  = bih[n] + bhh[n];
        float bz_  = bih[128 + n] + bhh[128 + n];
        float bin_ = bih[256 + n];
        float bhn_ = bhh[256 + n];
        #pragma unroll
        for (int r = 0; r < 4; ++r) {
            int row = m0 + lhi * 4 + r;
            float rr = 1.f / (1.f + expf(-(gr[nt][r] + br_)));
            float zz = 1.f / (1.f + expf(-(gz[nt][r] + bz_)));
            float nn = tanhf(gin[nt][r] + bin_ + rr * (ghn[nt][r] + bhn_));
            float hv = b2f(sm.p2.hbf[row][n]);
            float hnv = (1.f - zz) * nn + zz * hv;
            sm.p2.hnew[row][n] = f2b(hnv);
            long e = e0 + row;
            if (e < E_TOTAL) hout[e * 128 + n] = hnv;
        }
    }
    __syncthreads();

    // ---------------- Phase 5: x_out = h_new @ Wx^T + bx ----------------
    f32x4 a3[4];
    #pragma unroll
    for (int nt = 0; nt < 4; ++nt) a3[nt] = (f32x4){0.f, 0.f, 0.f, 0.f};
    {
        const unsigned short* wxp = Wxbf + (size_t)llo * 128 + lhi * 8;
        for (int k0 = 0; k0 < 128; k0 += 32) {
            bf16x8 a = *(const bf16x8*)&sm.p2.hnew[m0 + llo][k0 + lhi * 8];
            #pragma unroll
            for (int nt = 0; nt < 4; ++nt) {
                bf16x8 b = *(const bf16x8*)(wxp + (nt * 16) * 128 + k0);
                a3[nt] = MFMA(a, b, a3[nt]);
            }
        }
    }
    #pragma unroll
    for (int nt = 0; nt < 4; ++nt) {
        int n = nt * 16 + llo;
        float bb = bx[n];
        #pragma unroll
        for (int r = 0; r < 4; ++r) {
            long e = e0 + m0 + lhi * 4 + r;
            if (e < E_TOTAL) xout[e * 64 + n] = a3[nt][r] + bb;
        }
    }
}

extern "C" void kernel_launch(void* const* d_in, const int* in_sizes, int n_in,
                              void* d_out, int out_size, void* d_ws, size_t ws_size,
                              hipStream_t stream)
{
    const float* src   = (const float*)d_in[0];
    const float* dst   = (const float*)d_in[1];
    const float* eat   = (const float*)d_in[2];
    const float* hin   = (const float*)d_in[3];
    const float* u     = (const float*)d_in[4];
    const int*   bat   = (const int*)d_in[5];
    const float* wind  = (const float*)d_in[6];
    const float* Ww    = (const float*)d_in[7];
    const float* bw    = (const float*)d_in[8];
    const float* gw    = (const float*)d_in[9];
    const float* betaw = (const float*)d_in[10];
    const float* W1    = (const float*)d_in[11];
    const float* b1    = (const float*)d_in[12];
    const float* g1    = (const float*)d_in[13];
    const float* beta1 = (const float*)d_in[14];
    const float* Wih   = (const float*)d_in[15];
    const float* Whh   = (const float*)d_in[16];
    const float* bih   = (const float*)d_in[17];
    const float* bhh   = (const float*)d_in[18];
    const float* Wx    = (const float*)d_in[19];
    const float* bx    = (const float*)d_in[20];

    unsigned short* wbuf = (unsigned short*)d_ws;   // 155648 bf16 = 304 KB
    wconv_kernel<<<608, 256, 0, stream>>>(W1, Wih, Whh, Wx, wbuf);

    float* xout = (float*)d_out;
    float* hout = xout + (size_t)E_TOTAL * 64;
    int blocks = (E_TOTAL + 63) / 64;
    edge_model_kernel<<<blocks, 256, 0, stream>>>(
        src, dst, eat, hin, u, bat, wind, Ww, bw, gw, betaw,
        b1, g1, beta1, bih, bhh, bx,
        wbuf, wbuf + 49152, wbuf + 98304, wbuf + 147456,
        xout, hout);
}

// Round 2
// 1030.793 us; speedup vs baseline: 2.0065x; 2.0065x over previous
//
#include <hip/hip_runtime.h>
#include <hip/hip_bf16.h>

#define E_TOTAL 500000
#define NTILES ((E_TOTAL + 63) / 64)   // 7813
#define NBLOCKS 256

typedef __attribute__((ext_vector_type(8))) short bf16x8;
typedef __attribute__((ext_vector_type(4))) float f32x4;

#define MFMA(a, b, c) __builtin_amdgcn_mfma_f32_16x16x32_bf16((a), (b), (c), 0, 0, 0)

__device__ __forceinline__ unsigned short f2b(float f) {
    return __builtin_bit_cast(unsigned short, __float2bfloat16(f));
}
__device__ __forceinline__ float b2f(unsigned short s) {
    return __bfloat162float(__builtin_bit_cast(__hip_bfloat16, s));
}
__device__ __forceinline__ float sigm(float x) {
    return 1.f / (1.f + __expf(-x));
}
__device__ __forceinline__ float tanh_fast(float x) {
    float t = __expf(-2.f * x);
    return (1.f - t) / (1.f + t);
}

// f32 -> bf16 weight pre-conversion into workspace (runs every call; cheap).
__global__ void wconv_kernel(const float* __restrict__ W1, const float* __restrict__ Wih,
                             const float* __restrict__ Whh, const float* __restrict__ Wx,
                             unsigned short* __restrict__ out) {
    int i = blockIdx.x * 256 + threadIdx.x;
    if (i >= 155648) return;
    float v;
    if      (i < 49152)  v = W1[i];
    else if (i < 98304)  v = Wih[i - 49152];
    else if (i < 147456) v = Whh[i - 98304];
    else                 v = Wx[i - 147456];
    out[i] = f2b(v);
}

// Non-aliased LDS: 50176 + 3*17408 + 2*2048 = 106496 B (1 block/CU).
struct Smem {
    unsigned short x1[64][392];    // concat input, stride 392 (2-way bank alias on b128 reads)
    unsigned short y[64][136];     // post-mlp1 activations
    unsigned short hbf[64][136];   // h staged bf16
    unsigned short hnew[64][136];  // GRU output
    float lns[64][8];              // LN partial sums (per wave)
    float ln2[64][8];              // LN partial sumsq
};

__global__ __launch_bounds__(512, 2) void edge_model_kernel(
    const float* __restrict__ src, const float* __restrict__ dst,
    const float* __restrict__ eat, const float* __restrict__ hin,
    const float* __restrict__ u, const int* __restrict__ batch,
    const float* __restrict__ winding,
    const float* __restrict__ Ww, const float* __restrict__ bw,
    const float* __restrict__ gw, const float* __restrict__ betaw,
    const float* __restrict__ b1, const float* __restrict__ g1,
    const float* __restrict__ beta1,
    const float* __restrict__ bih, const float* __restrict__ bhh,
    const float* __restrict__ bx,
    const unsigned short* __restrict__ W1bf, const unsigned short* __restrict__ Wihbf,
    const unsigned short* __restrict__ Whhbf, const unsigned short* __restrict__ Wxbf,
    float* __restrict__ xout, float* __restrict__ hout)
{
    __shared__ Smem sm;
    const int tid  = threadIdx.x;
    const int wave = tid >> 6;        // 0..7, owns output cols [16w, 16w+16)
    const int lane = tid & 63;
    const int lhi  = lane >> 4;       // 0..3
    const int llo  = lane & 15;       // 0..15
    const int n    = wave * 16 + llo; // owned output column

    // ---- register-resident weight slices (loaded once, reused over ~30 tiles) ----
    bf16x8 w1f[12];                   // W1 cols [n], all 384 k   -> 48 VGPR
    {
        const unsigned short* p = W1bf + (size_t)n * 384 + lhi * 8;
        #pragma unroll
        for (int ks = 0; ks < 12; ++ks) w1f[ks] = *(const bf16x8*)(p + ks * 32);
    }
    bf16x8 wif[3][4], whf[3][4];      // GRU gate slices          -> 96 VGPR
    #pragma unroll
    for (int g = 0; g < 3; ++g) {
        const unsigned short* pi = Wihbf + (size_t)(g * 128 + n) * 128 + lhi * 8;
        const unsigned short* ph = Whhbf + (size_t)(g * 128 + n) * 128 + lhi * 8;
        #pragma unroll
        for (int ks = 0; ks < 4; ++ks) {
            wif[g][ks] = *(const bf16x8*)(pi + ks * 32);
            whf[g][ks] = *(const bf16x8*)(ph + ks * 32);
        }
    }
    const float b1v  = b1[n], g1v = g1[n], be1v = beta1[n];
    const float br_  = bih[n] + bhh[n];
    const float bz_  = bih[128 + n] + bhh[128 + n];
    const float bin_ = bih[256 + n];
    const float bhn_ = bhh[256 + n];
    const float bxv  = (wave < 4) ? bx[n] : 0.f;

    for (int tile = blockIdx.x; tile < NTILES; tile += NBLOCKS) {
        const size_t e0 = (size_t)tile * 64;

        // ---------------- stage x1 cols 0..255 (src|dst|eat|u[batch]) ----------------
        #pragma unroll
        for (int it = 0; it < 2; ++it) {
            int q   = it * 512 + tid;            // 1024 float4-quads
            int row = q >> 4;
            int c4  = (q & 15) << 2;
            size_t e = e0 + row; if (e >= E_TOTAL) e = E_TOTAL - 1;
            float4 a = *(const float4*)(src + e * 64 + c4);
            float4 b = *(const float4*)(dst + e * 64 + c4);
            float4 c = *(const float4*)(eat + e * 64 + c4);
            int bi   = batch[e];
            float4 d = *(const float4*)(u + (size_t)bi * 64 + c4);
            unsigned short* xr = sm.x1[row];
            ushort4 pa; pa.x=f2b(a.x); pa.y=f2b(a.y); pa.z=f2b(a.z); pa.w=f2b(a.w);
            ushort4 pb; pb.x=f2b(b.x); pb.y=f2b(b.y); pb.z=f2b(b.z); pb.w=f2b(b.w);
            ushort4 pc; pc.x=f2b(c.x); pc.y=f2b(c.y); pc.z=f2b(c.z); pc.w=f2b(c.w);
            ushort4 pd; pd.x=f2b(d.x); pd.y=f2b(d.y); pd.z=f2b(d.z); pd.w=f2b(d.w);
            *(ushort4*)(xr + c4)       = pa;
            *(ushort4*)(xr + 64 + c4)  = pb;
            *(ushort4*)(xr + 128 + c4) = pc;
            *(ushort4*)(xr + 192 + c4) = pd;
        }
        // ---------------- stage h tile as bf16 ----------------
        #pragma unroll
        for (int it = 0; it < 4; ++it) {
            int q   = it * 512 + tid;            // 2048 float4-quads
            int row = q >> 5;
            int c4  = (q & 31) << 2;
            size_t e = e0 + row; if (e >= E_TOTAL) e = E_TOTAL - 1;
            float4 v = *(const float4*)(hin + e * 128 + c4);
            ushort4 p; p.x=f2b(v.x); p.y=f2b(v.y); p.z=f2b(v.z); p.w=f2b(v.w);
            *(ushort4*)(sm.hbf[row] + c4) = p;
        }
        // ---------------- winding MLP: Linear(2->128)+LN+ReLU, 8 threads/row ----------------
        {
            int row = tid >> 3;
            int seg = tid & 7;
            size_t e = e0 + row; if (e >= E_TOTAL) e = E_TOTAL - 1;
            float wi0 = winding[e * 2], wi1 = winding[e * 2 + 1];
            float vals[16]; float s = 0.f, s2 = 0.f;
            #pragma unroll
            for (int j = 0; j < 16; ++j) {
                int jj = seg * 16 + j;
                float v = fmaf(wi0, Ww[2 * jj], fmaf(wi1, Ww[2 * jj + 1], bw[jj]));
                vals[j] = v; s += v; s2 += v * v;
            }
            s  += __shfl_xor(s, 1);  s  += __shfl_xor(s, 2);  s  += __shfl_xor(s, 4);
            s2 += __shfl_xor(s2, 1); s2 += __shfl_xor(s2, 2); s2 += __shfl_xor(s2, 4);
            float mean = s * (1.f / 128.f);
            float var  = fmaxf(s2 * (1.f / 128.f) - mean * mean, 0.f);
            float inv  = rsqrtf(var + 1e-5f);
            #pragma unroll
            for (int j = 0; j < 16; ++j) {
                int jj = seg * 16 + j;
                float v = (vals[j] - mean) * inv * gw[jj] + betaw[jj];
                sm.x1[row][256 + jj] = f2b(fmaxf(v, 0.f));
            }
        }
        __syncthreads();

        // ---------------- GEMM1: acc[mt] = x1 @ W1^T (cols n), all 64 rows ----------------
        f32x4 acc[4];
        #pragma unroll
        for (int mt = 0; mt < 4; ++mt) acc[mt] = (f32x4){0.f, 0.f, 0.f, 0.f};
        #pragma unroll
        for (int ks = 0; ks < 12; ++ks) {
            #pragma unroll
            for (int mt = 0; mt < 4; ++mt) {
                bf16x8 a = *(const bf16x8*)&sm.x1[mt * 16 + llo][ks * 32 + lhi * 8];
                acc[mt] = MFMA(a, w1f[ks], acc[mt]);
            }
        }
        // bias + per-wave LN partials (sum over this wave's 16 cols via shfl)
        #pragma unroll
        for (int mt = 0; mt < 4; ++mt) {
            #pragma unroll
            for (int r = 0; r < 4; ++r) {
                float v = acc[mt][r] + b1v;
                acc[mt][r] = v;
                float s = v, s2 = v * v;
                s  += __shfl_xor(s, 1);  s  += __shfl_xor(s, 2);
                s  += __shfl_xor(s, 4);  s  += __shfl_xor(s, 8);
                s2 += __shfl_xor(s2, 1); s2 += __shfl_xor(s2, 2);
                s2 += __shfl_xor(s2, 4); s2 += __shfl_xor(s2, 8);
                if (llo == 0) {
                    int row = mt * 16 + lhi * 4 + r;
                    sm.lns[row][wave] = s;
                    sm.ln2[row][wave] = s2;
                }
            }
        }
        __syncthreads();
        // LN apply + ReLU + y write (bf16)
        #pragma unroll
        for (int mt = 0; mt < 4; ++mt) {
            #pragma unroll
            for (int r = 0; r < 4; ++r) {
                int row = mt * 16 + lhi * 4 + r;
                float4 sa = *(const float4*)&sm.lns[row][0];
                float4 sb = *(const float4*)&sm.lns[row][4];
                float4 ta = *(const float4*)&sm.ln2[row][0];
                float4 tb = *(const float4*)&sm.ln2[row][4];
                float s  = sa.x + sa.y + sa.z + sa.w + sb.x + sb.y + sb.z + sb.w;
                float s2 = ta.x + ta.y + ta.z + ta.w + tb.x + tb.y + tb.z + tb.w;
                float mean = s * (1.f / 128.f);
                float var  = fmaxf(s2 * (1.f / 128.f) - mean * mean, 0.f);
                float inv  = rsqrtf(var + 1e-5f);
                float v = (acc[mt][r] - mean) * inv * g1v + be1v;
                sm.y[row][n] = f2b(fmaxf(v, 0.f));
            }
        }
        __syncthreads();

        // ---------------- GRU gates (two 32-row halves to bound VGPRs) ----------------
        #pragma unroll
        for (int mh = 0; mh < 2; ++mh) {
            f32x4 ar[2], az[2], an_[2], ah_[2];
            #pragma unroll
            for (int m2 = 0; m2 < 2; ++m2) {
                ar[m2] = (f32x4){0.f,0.f,0.f,0.f}; az[m2] = (f32x4){0.f,0.f,0.f,0.f};
                an_[m2] = (f32x4){0.f,0.f,0.f,0.f}; ah_[m2] = (f32x4){0.f,0.f,0.f,0.f};
            }
            #pragma unroll
            for (int ks = 0; ks < 4; ++ks) {
                #pragma unroll
                for (int m2 = 0; m2 < 2; ++m2) {
                    int mr = (mh * 2 + m2) * 16 + llo;
                    bf16x8 ay = *(const bf16x8*)&sm.y[mr][ks * 32 + lhi * 8];
                    bf16x8 ah = *(const bf16x8*)&sm.hbf[mr][ks * 32 + lhi * 8];
                    ar[m2]  = MFMA(ay, wif[0][ks], ar[m2]);
                    ar[m2]  = MFMA(ah, whf[0][ks], ar[m2]);
                    az[m2]  = MFMA(ay, wif[1][ks], az[m2]);
                    az[m2]  = MFMA(ah, whf[1][ks], az[m2]);
                    an_[m2] = MFMA(ay, wif[2][ks], an_[m2]);
                    ah_[m2] = MFMA(ah, whf[2][ks], ah_[m2]);
                }
            }
            #pragma unroll
            for (int m2 = 0; m2 < 2; ++m2) {
                #pragma unroll
                for (int r = 0; r < 4; ++r) {
                    int row = (mh * 2 + m2) * 16 + lhi * 4 + r;
                    float rr = sigm(ar[m2][r] + br_);
                    float zz = sigm(az[m2][r] + bz_);
                    float nn = tanh_fast(an_[m2][r] + bin_ + rr * (ah_[m2][r] + bhn_));
                    float hv = b2f(sm.hbf[row][n]);
                    float hnv = (1.f - zz) * nn + zz * hv;
                    sm.hnew[row][n] = f2b(hnv);
                    size_t e = e0 + row;
                    if (e < E_TOTAL) hout[e * 128 + n] = hnv;
                }
            }
        }
        __syncthreads();

        // ---------------- GEMM3: xout = h_new @ Wx^T + bx (waves 0..3) ----------------
        if (wave < 4) {
            f32x4 a3[4];
            #pragma unroll
            for (int mt = 0; mt < 4; ++mt) a3[mt] = (f32x4){0.f, 0.f, 0.f, 0.f};
            const unsigned short* wxp = Wxbf + (size_t)n * 128 + lhi * 8;
            #pragma unroll
            for (int ks = 0; ks < 4; ++ks) {
                bf16x8 b = *(const bf16x8*)(wxp + ks * 32);
                #pragma unroll
                for (int mt = 0; mt < 4; ++mt) {
                    bf16x8 a = *(const bf16x8*)&sm.hnew[mt * 16 + llo][ks * 32 + lhi * 8];
                    a3[mt] = MFMA(a, b, a3[mt]);
                }
            }
            #pragma unroll
            for (int mt = 0; mt < 4; ++mt) {
                #pragma unroll
                for (int r = 0; r < 4; ++r) {
                    size_t e = e0 + mt * 16 + lhi * 4 + r;
                    if (e < E_TOTAL) xout[e * 64 + n] = a3[mt][r] + bxv;
                }
            }
        }
        __syncthreads();   // protect LDS before next tile's staging
    }
}

extern "C" void kernel_launch(void* const* d_in, const int* in_sizes, int n_in,
                              void* d_out, int out_size, void* d_ws, size_t ws_size,
                              hipStream_t stream)
{
    const float* src   = (const float*)d_in[0];
    const float* dst   = (const float*)d_in[1];
    const float* eat   = (const float*)d_in[2];
    const float* hin   = (const float*)d_in[3];
    const float* u     = (const float*)d_in[4];
    const int*   bat   = (const int*)d_in[5];
    const float* wind  = (const float*)d_in[6];
    const float* Ww    = (const float*)d_in[7];
    const float* bw    = (const float*)d_in[8];
    const float* gw    = (const float*)d_in[9];
    const float* betaw = (const float*)d_in[10];
    const float* W1    = (const float*)d_in[11];
    const float* b1    = (const float*)d_in[12];
    const float* g1    = (const float*)d_in[13];
    const float* beta1 = (const float*)d_in[14];
    const float* Wih   = (const float*)d_in[15];
    const float* Whh   = (const float*)d_in[16];
    const float* bih   = (const float*)d_in[17];
    const float* bhh   = (const float*)d_in[18];
    const float* Wx    = (const float*)d_in[19];
    const float* bx    = (const float*)d_in[20];

    unsigned short* wbuf = (unsigned short*)d_ws;   // 155648 bf16 = 304 KB
    wconv_kernel<<<608, 256, 0, stream>>>(W1, Wih, Whh, Wx, wbuf);

    float* xout = (float*)d_out;
    float* hout = xout + (size_t)E_TOTAL * 64;
    edge_model_kernel<<<NBLOCKS, 512, 0, stream>>>(
        src, dst, eat, hin, u, bat, wind, Ww, bw, gw, betaw,
        b1, g1, beta1, bih, bhh, bx,
        wbuf, wbuf + 49152, wbuf + 98304, wbuf + 147456,
        xout, hout);
}